// Round 8
// baseline (1164.366 us; speedup 1.0000x reference)
//
#include <hip/hip_runtime.h>

#define NN 100000
#define NP 100096          // 782 * 128 = 391 * 256, padded row count
#define EE 300000
#define DIN 128
#define HD  256
#define HD2 512
#define NL  4
#define NG  512
#define BN_EPS 1e-5f

typedef __attribute__((ext_vector_type(8))) short s8v;      // bf16x8 frag (4 VGPRs)
typedef __attribute__((ext_vector_type(4))) float f4v;      // fp32x4 acc

typedef unsigned short ushort_t;

// float -> bf16, round-to-nearest-even
static __device__ inline ushort_t f2bf(float f) {
    unsigned u = __float_as_uint(f);
    unsigned r = (u + 0x7fffu + ((u >> 16) & 1u)) >> 16;
    return (ushort_t)r;
}
static __device__ inline float bf2f(ushort_t h) {
    return __uint_as_float(((unsigned)h) << 16);
}

// async global->LDS, 16B per lane; LDS dest = uniform base + lane*16
#define GLOAD_LDS16(g, l) __builtin_amdgcn_global_load_lds( \
    (const __attribute__((address_space(1))) unsigned int*)(const void*)(g), \
    (__attribute__((address_space(3))) unsigned int*)(void*)(l), 16, 0, 0)

// s_waitcnt immediates: vmcnt[3:0] | expcnt(7)<<4 | lgkmcnt(15)<<8 | vmcnt[5:4]<<14
#define WAITCNT_VM12 0xF7C
#define WAITCNT_VM6  0xF76
#define WAITCNT_VM0  0xF70

// ---------------------------------------------------------------------------
// bf16 MFMA GEMM:  C[.,ldc](bf16) = act( A[.,lda](bf16) @ BT[.,ldb]^T + bias )
// Block tile 256x128, BK=32, 256 threads = 4 waves, wave tile 64x128
// (acc[4][8] -> 32 MFMA per 12 ds_read_b128). 3-stage circular LDS pipeline
// (24 KB/stage, 72 KB): stage(it+3) issued after compute(it); graded
// vmcnt(12)/(6)/(0) waits keep 2 stages in flight across barriers.
// doStats: column sum/sumsq of fp32 output into stats via block reduce+atomics.
// ---------------------------------------------------------------------------
__global__ __launch_bounds__(256) void gemm_bf16(
    const ushort_t* __restrict__ A, int lda,
    const ushort_t* __restrict__ BT, int ldb,
    const float* __restrict__ bias,
    ushort_t* __restrict__ C, int ldc,
    int K, int doRelu,
    int doStats, float* __restrict__ stats, int Mvalid)
{
    extern __shared__ char smem[];
    ushort_t* lds = (ushort_t*)smem;            // 3 stages x (A 16KB | B 8KB)
    ushort_t* Cs  = lds;                        // epilogue reuse: 256x128 bf16 = 64 KB
    float* ssum   = (float*)(smem + 65536);     // [4][128]
    float* ssq    = ssum + 512;

    const int tid  = threadIdx.x;
    const int w    = tid >> 6;
    const int L    = tid & 63;
    const int lm   = L & 15;
    const int q    = L >> 4;
    const int row0 = blockIdx.x * 256;
    const int col0 = blockIdx.y * 128;

    const ushort_t* gAbase = A  + (size_t)lm * lda;
    const ushort_t* gBbase = BT + (size_t)lm * ldb;

    f4v acc[4][8] = {};

    const int niter = K >> 5;

    // stage(buf, k0): A = 16 tiles [16r x 32c] (4/wave), B = 8 tiles (2/wave);
    // 6 global_load_lds per thread per stage.
    #define STAGE(buf, k0) do {                                              \
        ushort_t* As_ = lds + (buf) * 12288;                                 \
        ushort_t* Bs_ = As_ + 8192;                                          \
        const int kk_ = (k0) + q * 8;                                        \
        _Pragma("unroll")                                                    \
        for (int i_ = 0; i_ < 4; ++i_) {                                     \
            const int tl_ = w * 4 + i_;                                      \
            GLOAD_LDS16(gAbase + (size_t)(row0 + tl_ * 16) * lda + kk_,      \
                        As_ + tl_ * 512);                                    \
        }                                                                    \
        _Pragma("unroll")                                                    \
        for (int i_ = 0; i_ < 2; ++i_) {                                     \
            const int tl_ = w * 2 + i_;                                      \
            GLOAD_LDS16(gBbase + (size_t)(col0 + tl_ * 16) * ldb + kk_,      \
                        Bs_ + tl_ * 512);                                    \
        }                                                                    \
    } while (0)

    STAGE(0, 0);
    if (niter > 1) STAGE(1, 32);
    if (niter > 2) STAGE(2, 64);

    int cur = 0;
    for (int it = 0; it < niter; ++it) {
        const int rem = niter - 1 - it;
        if (rem >= 2)      __builtin_amdgcn_s_waitcnt(WAITCNT_VM12);
        else if (rem == 1) __builtin_amdgcn_s_waitcnt(WAITCNT_VM6);
        else               __builtin_amdgcn_s_waitcnt(WAITCNT_VM0);
        __builtin_amdgcn_s_barrier();

        const ushort_t* Ab = lds + cur * 12288;
        const ushort_t* Bb = Ab + 8192;
        s8v a0 = *(const s8v*)&Ab[(4 * w + 0) * 512 + L * 8];
        s8v a1 = *(const s8v*)&Ab[(4 * w + 1) * 512 + L * 8];
        s8v a2 = *(const s8v*)&Ab[(4 * w + 2) * 512 + L * 8];
        s8v a3 = *(const s8v*)&Ab[(4 * w + 3) * 512 + L * 8];
#pragma unroll
        for (int nt = 0; nt < 8; ++nt) {
            s8v b = *(const s8v*)&Bb[nt * 512 + L * 8];
            acc[0][nt] = __builtin_amdgcn_mfma_f32_16x16x32_bf16(a0, b, acc[0][nt], 0, 0, 0);
            acc[1][nt] = __builtin_amdgcn_mfma_f32_16x16x32_bf16(a1, b, acc[1][nt], 0, 0, 0);
            acc[2][nt] = __builtin_amdgcn_mfma_f32_16x16x32_bf16(a2, b, acc[2][nt], 0, 0, 0);
            acc[3][nt] = __builtin_amdgcn_mfma_f32_16x16x32_bf16(a3, b, acc[3][nt], 0, 0, 0);
        }
        __builtin_amdgcn_s_barrier();      // all waves done reading buf(cur)
        if (it + 3 < niter) STAGE(cur, (it + 3) * 32);
        cur = (cur == 2) ? 0 : cur + 1;
    }
    #undef STAGE

    __syncthreads();    // drain before LDS reuse in epilogue

    // epilogue: bias + relu + cvt; C/D frag: col = lm, row = q*4 + r
    float cs[8] = {};
    float cq[8] = {};
#pragma unroll
    for (int mt = 0; mt < 4; ++mt) {
#pragma unroll
        for (int nt = 0; nt < 8; ++nt) {
            const float bj = bias[col0 + nt * 16 + lm];
            f4v v = acc[mt][nt];
#pragma unroll
            for (int r = 0; r < 4; ++r) {
                float f = v[r] + bj;
                if (doRelu) f = fmaxf(f, 0.f);
                const int row = (4 * w + mt) * 16 + q * 4 + r;
                const int col = nt * 16 + lm;
                Cs[row * 128 + col] = f2bf(f);
                if (doStats && (row0 + row) < Mvalid) {
                    cs[nt] += f;
                    cq[nt] += f * f;
                }
            }
        }
    }
    if (doStats) {
#pragma unroll
        for (int nt = 0; nt < 8; ++nt) {
            float s = cs[nt], sq = cq[nt];
            s  += __shfl_xor(s, 16, 64);  s  += __shfl_xor(s, 32, 64);
            sq += __shfl_xor(sq, 16, 64); sq += __shfl_xor(sq, 32, 64);
            cs[nt] = s; cq[nt] = sq;
        }
    }
    __syncthreads();
    if (doStats && q == 0) {
#pragma unroll
        for (int nt = 0; nt < 8; ++nt) {
            ssum[w * 128 + nt * 16 + lm] = cs[nt];
            ssq [w * 128 + nt * 16 + lm] = cq[nt];
        }
    }
#pragma unroll
    for (int i = 0; i < 16; ++i) {
        const int idx = i * 256 + tid;          // 4096 chunks of 8 bf16
        const int row = idx >> 4, ch = idx & 15;
        s8v val = *(const s8v*)&Cs[row * 128 + ch * 8];
        *(s8v*)(C + (size_t)(row0 + row) * ldc + col0 + ch * 8) = val;
    }
    if (doStats) {
        __syncthreads();
        if (tid < 128) {
            const float s  = ssum[tid] + ssum[128 + tid] + ssum[256 + tid] + ssum[384 + tid];
            const float sq = ssq[tid]  + ssq[128 + tid]  + ssq[256 + tid]  + ssq[384 + tid];
            unsafeAtomicAdd(&stats[col0 + tid], s);
            unsafeAtomicAdd(&stats[HD + col0 + tid], sq);
        }
    }
}

// ---------------------------------------------------------------------------
__global__ __launch_bounds__(256) void transpose_cvt_kernel(
    const float* __restrict__ in, ushort_t* __restrict__ out, int R, int C)
{
    __shared__ float tile[32][33];
    const int bx = blockIdx.x * 32;
    const int by = blockIdx.y * 32;
    const int tx = threadIdx.x & 31;
    const int ty = threadIdx.x >> 5;
#pragma unroll
    for (int i = 0; i < 32; i += 8)
        tile[ty + i][tx] = in[(size_t)(by + ty + i) * C + bx + tx];
    __syncthreads();
#pragma unroll
    for (int i = 0; i < 32; i += 8)
        out[(size_t)(bx + ty + i) * R + by + tx] = f2bf(tile[tx][ty + i]);
}

__global__ __launch_bounds__(256) void cvt_kernel(
    const float* __restrict__ in, ushort_t* __restrict__ out, long n4)
{
    const long i = (long)blockIdx.x * 256 + threadIdx.x;
    if (i >= n4) return;
    const float4 v = ((const float4*)in)[i];
    ushort4 o;
    o.x = f2bf(v.x); o.y = f2bf(v.y); o.z = f2bf(v.z); o.w = f2bf(v.w);
    ((ushort4*)out)[i] = o;
}

__global__ __launch_bounds__(256) void zero_kernel(float* __restrict__ p, long n4)
{
    const long i = (long)blockIdx.x * 256 + threadIdx.x;
    if (i < n4) ((float4*)p)[i] = make_float4(0.f, 0.f, 0.f, 0.f);
}

// identity scale/shift + zeroed stats (once per call, before layer 0)
__global__ __launch_bounds__(256) void init_bn_kernel(
    float* __restrict__ sscale, float* __restrict__ sshift,
    float* __restrict__ stats)
{
    const int t = threadIdx.x;
    sscale[t] = 1.f;
    sshift[t] = 0.f;
    stats[t] = 0.f;
    stats[HD + t] = 0.f;
}

// scale/shift from stats; re-zero stats for the next layer
__global__ __launch_bounds__(256) void bnprep_kernel(
    float* __restrict__ stats, const float* __restrict__ gamma,
    const float* __restrict__ beta, float* __restrict__ sscale,
    float* __restrict__ sshift, int Nn)
{
    const int t = threadIdx.x;
    const float invN = 1.0f / (float)Nn;
    const float mu  = stats[t] * invN;
    const float var = stats[HD + t] * invN - mu * mu;
    const float inv = rsqrtf(var + BN_EPS);
    const float sc  = gamma[t] * inv;
    sscale[t] = sc;
    sshift[t] = beta[t] - mu * sc;
    stats[t] = 0.f;
    stats[HD + t] = 0.f;
}

// ---------------- CSR build (per call; edges are layer-invariant) -----------
__global__ __launch_bounds__(256) void hist_kernel(
    const int* __restrict__ dst, int* __restrict__ deg, int E)
{
    const int e = blockIdx.x * 256 + threadIdx.x;
    if (e < E) atomicAdd(&deg[dst[e]], 1);
}

__global__ __launch_bounds__(256) void scan1_kernel(
    const int* __restrict__ deg, int* __restrict__ partial,
    int* __restrict__ bsums, int n)
{
    __shared__ int tmp[256];
    const int i = blockIdx.x * 256 + threadIdx.x;
    const int v = (i < n) ? deg[i] : 0;
    tmp[threadIdx.x] = v;
    __syncthreads();
    for (int off = 1; off < 256; off <<= 1) {
        const int t = (threadIdx.x >= off) ? tmp[threadIdx.x - off] : 0;
        __syncthreads();
        tmp[threadIdx.x] += t;
        __syncthreads();
    }
    if (i < n) partial[i] = tmp[threadIdx.x] - v;
    if (threadIdx.x == 255) bsums[blockIdx.x] = tmp[255];
}

__global__ __launch_bounds__(512) void scan2_kernel(int* __restrict__ bsums, int nb)
{
    __shared__ int tmp[512];
    const int i = threadIdx.x;
    const int v = (i < nb) ? bsums[i] : 0;
    tmp[i] = v;
    __syncthreads();
    for (int off = 1; off < 512; off <<= 1) {
        const int t = (i >= off) ? tmp[i - off] : 0;
        __syncthreads();
        tmp[i] += t;
        __syncthreads();
    }
    if (i < nb) bsums[i] = tmp[i] - v;
}

__global__ __launch_bounds__(256) void scan3_kernel(
    const int* __restrict__ partial, const int* __restrict__ bsums,
    int* __restrict__ offs, int* __restrict__ cursor, int n)
{
    const int i = blockIdx.x * 256 + threadIdx.x;
    if (i < n) {
        const int o = partial[i] + bsums[blockIdx.x];
        offs[i] = o;
        cursor[i] = o;
    }
}

__global__ __launch_bounds__(256) void scatter_kernel(
    const int* __restrict__ src, const int* __restrict__ dst,
    int* __restrict__ cursor, int* __restrict__ srcSorted, int E)
{
    const int e = blockIdx.x * 256 + threadIdx.x;
    if (e >= E) return;
    const int p = atomicAdd(&cursor[dst[e]], 1);
    srcSorted[p] = src[e];
}

// ---------------------------------------------------------------------------
// out[n] = bf16( (1+eps)*y[n] + sum_{s in nbrs(n)} y[s] ),
// where y[i] = relu( z[i]*sscale + sshift )  (BN applied on the fly).
__global__ __launch_bounds__(256) void aggregate_kernel(
    const ushort_t* __restrict__ z, const int* __restrict__ offs,
    const int* __restrict__ deg, const int* __restrict__ srcSorted,
    const float* __restrict__ epsArr, int epsIdx,
    const float* __restrict__ sscale, const float* __restrict__ sshift,
    ushort_t* __restrict__ out)
{
    const int n = blockIdx.x * 4 + (threadIdx.x >> 6);
    const int t = threadIdx.x & 63;
    const float4 sc = *(const float4*)(sscale + t * 4);
    const float4 sh = *(const float4*)(sshift + t * 4);
    const int start = offs[n];
    const int dc = deg[n];
    float a0 = 0.f, a1 = 0.f, a2 = 0.f, a3 = 0.f;
    for (int j = 0; j < dc; ++j) {
        const int s = srcSorted[start + j];
        const ushort4 u = *(const ushort4*)(z + (size_t)s * HD + t * 4);
        a0 += fmaxf(bf2f(u.x) * sc.x + sh.x, 0.f);
        a1 += fmaxf(bf2f(u.y) * sc.y + sh.y, 0.f);
        a2 += fmaxf(bf2f(u.z) * sc.z + sh.z, 0.f);
        a3 += fmaxf(bf2f(u.w) * sc.w + sh.w, 0.f);
    }
    const float se = 1.0f + epsArr[epsIdx];
    const ushort4 hs = *(const ushort4*)(z + (size_t)n * HD + t * 4);
    ushort4 o;
    o.x = f2bf(se * fmaxf(bf2f(hs.x) * sc.x + sh.x, 0.f) + a0);
    o.y = f2bf(se * fmaxf(bf2f(hs.y) * sc.y + sh.y, 0.f) + a1);
    o.z = f2bf(se * fmaxf(bf2f(hs.z) * sc.z + sh.z, 0.f) + a2);
    o.w = f2bf(se * fmaxf(bf2f(hs.w) * sc.w + sh.w, 0.f) + a3);
    *(ushort4*)(out + (size_t)n * HD + t * 4) = o;
}

// ---------------------------------------------------------------------------
// Fused mean-pool + head, BN on the fly. Wave w handles rows start+w, +4...;
// lane L handles cols 4L..4L+3 (ushort4). Two row-streams for ILP.
__global__ __launch_bounds__(256) void pool_head_kernel(
    const ushort_t* __restrict__ z, const int* __restrict__ batch,
    const float* __restrict__ sscale, const float* __restrict__ sshift,
    const float* __restrict__ Wp1, const float* __restrict__ bp1,
    const float* __restrict__ Wp2, const float* __restrict__ bp2,
    float* __restrict__ out)
{
    __shared__ float poolw[4][HD];
    __shared__ float pool[HD];
    __shared__ float red[128];
    __shared__ int seg[2];
    const int g = blockIdx.x;
    const int t = threadIdx.x;
    const int w = t >> 6;
    const int L = t & 63;
    if (t == 0) {
        int lo = 0, hi = NN;
        while (lo < hi) { const int m = (lo + hi) >> 1; if (batch[m] < g) lo = m + 1; else hi = m; }
        seg[0] = lo;
        hi = NN;
        while (lo < hi) { const int m = (lo + hi) >> 1; if (batch[m] < g + 1) lo = m + 1; else hi = m; }
        seg[1] = lo;
    }
    __syncthreads();
    const int start = seg[0], end = seg[1];
    const int c0 = L * 4;
    const float4 sc = *(const float4*)(sscale + c0);
    const float4 sh = *(const float4*)(sshift + c0);
    float a0 = 0.f, a1 = 0.f, a2 = 0.f, a3 = 0.f;
    float b0 = 0.f, b1 = 0.f, b2 = 0.f, b3 = 0.f;
    int r = start + w;
    for (; r + 4 < end; r += 8) {
        const ushort4 u = *(const ushort4*)(z + (size_t)r * HD + c0);
        const ushort4 v = *(const ushort4*)(z + (size_t)(r + 4) * HD + c0);
        a0 += fmaxf(bf2f(u.x) * sc.x + sh.x, 0.f);
        a1 += fmaxf(bf2f(u.y) * sc.y + sh.y, 0.f);
        a2 += fmaxf(bf2f(u.z) * sc.z + sh.z, 0.f);
        a3 += fmaxf(bf2f(u.w) * sc.w + sh.w, 0.f);
        b0 += fmaxf(bf2f(v.x) * sc.x + sh.x, 0.f);
        b1 += fmaxf(bf2f(v.y) * sc.y + sh.y, 0.f);
        b2 += fmaxf(bf2f(v.z) * sc.z + sh.z, 0.f);
        b3 += fmaxf(bf2f(v.w) * sc.w + sh.w, 0.f);
    }
    if (r < end) {
        const ushort4 u = *(const ushort4*)(z + (size_t)r * HD + c0);
        a0 += fmaxf(bf2f(u.x) * sc.x + sh.x, 0.f);
        a1 += fmaxf(bf2f(u.y) * sc.y + sh.y, 0.f);
        a2 += fmaxf(bf2f(u.z) * sc.z + sh.z, 0.f);
        a3 += fmaxf(bf2f(u.w) * sc.w + sh.w, 0.f);
    }
    poolw[w][c0 + 0] = a0 + b0;
    poolw[w][c0 + 1] = a1 + b1;
    poolw[w][c0 + 2] = a2 + b2;
    poolw[w][c0 + 3] = a3 + b3;
    __syncthreads();
    const float invC = 1.0f / (float)max(end - start, 1);
    pool[t] = (poolw[0][t] + poolw[1][t] + poolw[2][t] + poolw[3][t]) * invC;
    __syncthreads();
    if (t < 128) {
        float acc = 0.f;
#pragma unroll 4
        for (int k = 0; k < HD; ++k)
            acc += pool[k] * Wp1[k * 128 + t];
        red[t] = fmaxf(acc + bp1[t], 0.f) * Wp2[t];
    }
    __syncthreads();
    for (int sft = 64; sft > 0; sft >>= 1) {
        if (t < sft) red[t] += red[t + sft];
        __syncthreads();
    }
    if (t == 0) out[g] = red[0] + bp2[0];
}

// ---------------------------------------------------------------------------
extern "C" void kernel_launch(void* const* d_in, const int* in_sizes, int n_in,
                              void* d_out, int out_size, void* d_ws, size_t ws_size,
                              hipStream_t stream)
{
    const float* x     = (const float*)d_in[0];
    const int*   ei    = (const int*)  d_in[1];
    const int*   batch = (const int*)  d_in[2];
    const float* W_in  = (const float*)d_in[3];
    const float* b_in  = (const float*)d_in[4];
    const float* eps   = (const float*)d_in[5];
    const float* W1    = (const float*)d_in[6];
    const float* b1    = (const float*)d_in[7];
    const float* W2    = (const float*)d_in[8];
    const float* b2    = (const float*)d_in[9];
    const float* gamma = (const float*)d_in[10];
    const float* beta  = (const float*)d_in[11];
    const float* Wp1   = (const float*)d_in[12];
    const float* bp1   = (const float*)d_in[13];
    const float* Wp2   = (const float*)d_in[14];
    const float* bp2   = (const float*)d_in[15];

    const int* srcIdx = ei;
    const int* dstIdx = ei + EE;

    // ---- workspace layout ----
    char* p = (char*)d_ws;
    ushort_t* zbuf    = (ushort_t*)p;  p += (size_t)NP * HD  * 2;   // pre-BN acts
    ushort_t* abuf    = (ushort_t*)p;  p += (size_t)NP * HD  * 2;   // aggregate out
    ushort_t* hidden  = (ushort_t*)p;  p += (size_t)NP * HD2 * 2;   // MLP hidden (x_bf alias)
    ushort_t* W1T     = (ushort_t*)p;  p += (size_t)NL * HD2 * HD * 2;
    ushort_t* W2T     = (ushort_t*)p;  p += (size_t)NL * HD * HD2 * 2;
    ushort_t* WinT    = (ushort_t*)p;  p += (size_t)HD * DIN * 2;
    int* deg          = (int*)p;       p += (size_t)NN * 4;
    int* partial      = (int*)p;       p += (size_t)NN * 4;
    int* bsums        = (int*)p;       p += 512 * 4;
    int* offs         = (int*)p;       p += (size_t)NN * 4;
    int* cursor       = (int*)p;       p += (size_t)NN * 4;
    int* srcSorted    = (int*)p;       p += (size_t)EE * 4;
    float* stats      = (float*)p;     p += 2 * HD * 4;
    float* sscale     = (float*)p;     p += HD * 4;
    float* sshift     = (float*)p;     p += HD * 4;
    ushort_t* x_bf    = hidden;        // GEMM0 A; clobbered later by GEMM1 out

    const int nb = (NN + 255) / 256;   // 391
    const int GEMM_LDS = 73728;        // 3 x 24KB stages; epilogue reuses

    // ---- BN identity + stats zero ----
    init_bn_kernel<<<1, 256, 0, stream>>>(sscale, sshift, stats);

    // ---- weight conversion (bf16, transposed) ----
    transpose_cvt_kernel<<<dim3(HD / 32, DIN / 32), 256, 0, stream>>>(W_in, WinT, DIN, HD);
    for (int l = 0; l < NL; ++l) {
        transpose_cvt_kernel<<<dim3(HD2 / 32, HD / 32), 256, 0, stream>>>(
            W1 + (size_t)l * HD * HD2, W1T + (size_t)l * HD2 * HD, HD, HD2);
        transpose_cvt_kernel<<<dim3(HD / 32, HD2 / 32), 256, 0, stream>>>(
            W2 + (size_t)l * HD2 * HD, W2T + (size_t)l * HD * HD2, HD2, HD);
    }
    cvt_kernel<<<(int)(((long)NN * DIN / 4 + 255) / 256), 256, 0, stream>>>(
        x, x_bf, (long)NN * DIN / 4);

    // ---- CSR build (once; edges layer-invariant) ----
    zero_kernel<<<(NN / 4 + 255) / 256, 256, 0, stream>>>((float*)deg, NN / 4);
    hist_kernel<<<(EE + 255) / 256, 256, 0, stream>>>(dstIdx, deg, EE);
    scan1_kernel<<<nb, 256, 0, stream>>>(deg, partial, bsums, NN);
    scan2_kernel<<<1, 512, 0, stream>>>(bsums, nb);
    scan3_kernel<<<nb, 256, 0, stream>>>(partial, bsums, offs, cursor, NN);
    scatter_kernel<<<(EE + 255) / 256, 256, 0, stream>>>(srcIdx, dstIdx, cursor, srcSorted, EE);

    // ---- input projection: zbuf = relu(x @ W_in + b_in)  (identity BN) ----
    gemm_bf16<<<dim3(NP / 256, HD / 128), 256, GEMM_LDS, stream>>>(
        x_bf, DIN, WinT, DIN, b_in, zbuf, HD, DIN, 1, 0, nullptr, 0);

    // ---- GIN layers ----
    for (int l = 0; l < NL; ++l) {
        aggregate_kernel<<<NN / 4, 256, 0, stream>>>(
            zbuf, offs, deg, srcSorted, eps, l, sscale, sshift, abuf);

        gemm_bf16<<<dim3(NP / 256, HD2 / 128), 256, GEMM_LDS, stream>>>(
            abuf, HD, W1T + (size_t)l * HD2 * HD, HD,
            b1 + (size_t)l * HD2, hidden, HD2, HD, 1, 0, nullptr, 0);

        gemm_bf16<<<dim3(NP / 256, HD / 128), 256, GEMM_LDS, stream>>>(
            hidden, HD2, W2T + (size_t)l * HD * HD2, HD2,
            b2 + (size_t)l * HD, zbuf, HD, HD2, 0, 1, stats, NN);

        bnprep_kernel<<<1, 256, 0, stream>>>(
            stats, gamma + (size_t)l * HD, beta + (size_t)l * HD, sscale, sshift, NN);
    }

    // ---- fused mean pool + head (BN on the fly) ----
    pool_head_kernel<<<NG, 256, 0, stream>>>(zbuf, batch, sscale, sshift,
                                             Wp1, bp1, Wp2, bp2, (float*)d_out);
}

// Round 9
// 943.932 us; speedup vs baseline: 1.2335x; 1.2335x over previous
//
#include <hip/hip_runtime.h>

#define NN 100000
#define NP 100096          // 782 * 128, padded row count
#define EE 300000
#define DIN 128
#define HD  256
#define HD2 512
#define NL  4
#define NG  512
#define BN_EPS 1e-5f

typedef __attribute__((ext_vector_type(8))) short s8v;      // bf16x8 frag (4 VGPRs)
typedef __attribute__((ext_vector_type(4))) float f4v;      // fp32x4 acc

typedef unsigned short ushort_t;

// float -> bf16, round-to-nearest-even
static __device__ inline ushort_t f2bf(float f) {
    unsigned u = __float_as_uint(f);
    unsigned r = (u + 0x7fffu + ((u >> 16) & 1u)) >> 16;
    return (ushort_t)r;
}
static __device__ inline float bf2f(ushort_t h) {
    return __uint_as_float(((unsigned)h) << 16);
}

// async global->LDS, 16B per lane; LDS dest = uniform base + lane*16
#define GLOAD_LDS16(g, l) __builtin_amdgcn_global_load_lds( \
    (const __attribute__((address_space(1))) unsigned int*)(const void*)(g), \
    (__attribute__((address_space(3))) unsigned int*)(void*)(l), 16, 0, 0)

// s_waitcnt immediates: vmcnt[3:0] | expcnt(7)<<4 | lgkmcnt(15)<<8 | vmcnt[5:4]<<14
#define WAITCNT_VM8 0xF78
#define WAITCNT_VM4 0xF74
#define WAITCNT_VM0 0xF70

// ---------------------------------------------------------------------------
// bf16 MFMA GEMM:  C[.,ldc](bf16) = act( A[.,lda](bf16) @ BT[.,ldb]^T + bias )
// Block tile 128x128, BK=32, 256 threads = 4 waves (r7 shape: 64 AGPR + ~80
// VGPR -> 3 waves/SIMD). 3-stage circular LDS pipeline (16 KB/stage, 48 KB):
// stage(it+3) issued after compute(it); graded vmcnt(8)/(4)/(0) keeps two
// stages in flight across barriers. 53 KB LDS -> 3 blocks/CU, matching regs.
// doStats: column sum/sumsq of fp32 output into stats via block reduce+atomics.
// ---------------------------------------------------------------------------
__global__ __launch_bounds__(256) void gemm_bf16(
    const ushort_t* __restrict__ A, int lda,
    const ushort_t* __restrict__ BT, int ldb,
    const float* __restrict__ bias,
    ushort_t* __restrict__ C, int ldc,
    int K, int doRelu,
    int doStats, float* __restrict__ stats, int Mvalid)
{
    extern __shared__ char smem[];
    ushort_t* lds = (ushort_t*)smem;            // 3 stages x (A 8KB | B 8KB)
    ushort_t* Cs  = lds;                        // epilogue reuse (32 KB)
    float* ssum   = (float*)(smem + 49152);     // [4][128]
    float* ssq    = ssum + 512;

    const int tid  = threadIdx.x;
    const int w    = tid >> 6;
    const int L    = tid & 63;
    const int lm   = L & 15;
    const int q    = L >> 4;
    const int row0 = blockIdx.x * 128;
    const int col0 = blockIdx.y * 128;

    const ushort_t* gAbase = A  + (size_t)lm * lda;
    const ushort_t* gBbase = BT + (size_t)lm * ldb;

    f4v acc[2][8] = {};

    const int niter = K >> 5;

    // stage(buf, k0): 8 A-tiles + 8 B-tiles of [16r x 32c]; 2 A + 2 B per wave;
    // 4 global_load_lds per thread per stage.
    #define STAGE(buf, k0) do {                                              \
        ushort_t* As_ = lds + (buf) * 8192;                                  \
        ushort_t* Bs_ = As_ + 4096;                                          \
        const int kk_ = (k0) + q * 8;                                        \
        _Pragma("unroll")                                                    \
        for (int i_ = 0; i_ < 2; ++i_) {                                     \
            const int tl_ = w * 2 + i_;                                      \
            GLOAD_LDS16(gAbase + (size_t)(row0 + tl_ * 16) * lda + kk_,      \
                        As_ + tl_ * 512);                                    \
            GLOAD_LDS16(gBbase + (size_t)(col0 + tl_ * 16) * ldb + kk_,      \
                        Bs_ + tl_ * 512);                                    \
        }                                                                    \
    } while (0)

    STAGE(0, 0);
    if (niter > 1) STAGE(1, 32);
    if (niter > 2) STAGE(2, 64);

    int cur = 0;
    for (int it = 0; it < niter; ++it) {
        const int rem = niter - 1 - it;
        if (rem >= 2)      __builtin_amdgcn_s_waitcnt(WAITCNT_VM8);
        else if (rem == 1) __builtin_amdgcn_s_waitcnt(WAITCNT_VM4);
        else               __builtin_amdgcn_s_waitcnt(WAITCNT_VM0);
        __builtin_amdgcn_s_barrier();

        const ushort_t* Ab = lds + cur * 8192;
        const ushort_t* Bb = Ab + 4096;
        s8v a0 = *(const s8v*)&Ab[(2 * w)     * 512 + L * 8];
        s8v a1 = *(const s8v*)&Ab[(2 * w + 1) * 512 + L * 8];
#pragma unroll
        for (int nt = 0; nt < 8; ++nt) {
            s8v b = *(const s8v*)&Bb[nt * 512 + L * 8];
            acc[0][nt] = __builtin_amdgcn_mfma_f32_16x16x32_bf16(a0, b, acc[0][nt], 0, 0, 0);
            acc[1][nt] = __builtin_amdgcn_mfma_f32_16x16x32_bf16(a1, b, acc[1][nt], 0, 0, 0);
        }
        __builtin_amdgcn_s_barrier();      // all waves done reading buf(cur)
        if (it + 3 < niter) STAGE(cur, (it + 3) * 32);
        cur = (cur == 2) ? 0 : cur + 1;
    }
    #undef STAGE

    __syncthreads();    // drain before LDS reuse in epilogue

    // epilogue: bias + relu + cvt; C/D frag: col = lm, row = q*4 + r
    float cs[8] = {};
    float cq[8] = {};
#pragma unroll
    for (int mt = 0; mt < 2; ++mt) {
#pragma unroll
        for (int nt = 0; nt < 8; ++nt) {
            const float bj = bias[col0 + nt * 16 + lm];
            f4v v = acc[mt][nt];
#pragma unroll
            for (int r = 0; r < 4; ++r) {
                float f = v[r] + bj;
                if (doRelu) f = fmaxf(f, 0.f);
                const int row = (2 * w + mt) * 16 + q * 4 + r;
                const int col = nt * 16 + lm;
                Cs[row * 128 + col] = f2bf(f);
                if (doStats && (row0 + row) < Mvalid) {
                    cs[nt] += f;
                    cq[nt] += f * f;
                }
            }
        }
    }
    if (doStats) {
#pragma unroll
        for (int nt = 0; nt < 8; ++nt) {
            float s = cs[nt], sq = cq[nt];
            s  += __shfl_xor(s, 16, 64);  s  += __shfl_xor(s, 32, 64);
            sq += __shfl_xor(sq, 16, 64); sq += __shfl_xor(sq, 32, 64);
            cs[nt] = s; cq[nt] = sq;
        }
    }
    __syncthreads();
    if (doStats && q == 0) {
#pragma unroll
        for (int nt = 0; nt < 8; ++nt) {
            ssum[w * 128 + nt * 16 + lm] = cs[nt];
            ssq [w * 128 + nt * 16 + lm] = cq[nt];
        }
    }
#pragma unroll
    for (int i = 0; i < 8; ++i) {
        const int idx = i * 256 + tid;
        const int row = idx >> 4, ch = idx & 15;
        s8v val = *(const s8v*)&Cs[row * 128 + ch * 8];
        *(s8v*)(C + (size_t)(row0 + row) * ldc + col0 + ch * 8) = val;
    }
    if (doStats) {
        __syncthreads();
        if (tid < 128) {
            const float s  = ssum[tid] + ssum[128 + tid] + ssum[256 + tid] + ssum[384 + tid];
            const float sq = ssq[tid]  + ssq[128 + tid]  + ssq[256 + tid]  + ssq[384 + tid];
            unsafeAtomicAdd(&stats[col0 + tid], s);
            unsafeAtomicAdd(&stats[HD + col0 + tid], sq);
        }
    }
}

// ---------------------------------------------------------------------------
__global__ __launch_bounds__(256) void transpose_cvt_kernel(
    const float* __restrict__ in, ushort_t* __restrict__ out, int R, int C)
{
    __shared__ float tile[32][33];
    const int bx = blockIdx.x * 32;
    const int by = blockIdx.y * 32;
    const int tx = threadIdx.x & 31;
    const int ty = threadIdx.x >> 5;
#pragma unroll
    for (int i = 0; i < 32; i += 8)
        tile[ty + i][tx] = in[(size_t)(by + ty + i) * C + bx + tx];
    __syncthreads();
#pragma unroll
    for (int i = 0; i < 32; i += 8)
        out[(size_t)(bx + ty + i) * R + by + tx] = f2bf(tile[tx][ty + i]);
}

__global__ __launch_bounds__(256) void cvt_kernel(
    const float* __restrict__ in, ushort_t* __restrict__ out, long n4)
{
    const long i = (long)blockIdx.x * 256 + threadIdx.x;
    if (i >= n4) return;
    const float4 v = ((const float4*)in)[i];
    ushort4 o;
    o.x = f2bf(v.x); o.y = f2bf(v.y); o.z = f2bf(v.z); o.w = f2bf(v.w);
    ((ushort4*)out)[i] = o;
}

__global__ __launch_bounds__(256) void zero_kernel(float* __restrict__ p, long n4)
{
    const long i = (long)blockIdx.x * 256 + threadIdx.x;
    if (i < n4) ((float4*)p)[i] = make_float4(0.f, 0.f, 0.f, 0.f);
}

// identity scale/shift + zeroed stats (once per call, before layer 0)
__global__ __launch_bounds__(256) void init_bn_kernel(
    float* __restrict__ sscale, float* __restrict__ sshift,
    float* __restrict__ stats)
{
    const int t = threadIdx.x;
    sscale[t] = 1.f;
    sshift[t] = 0.f;
    stats[t] = 0.f;
    stats[HD + t] = 0.f;
}

// scale/shift from stats; re-zero stats for the next layer
__global__ __launch_bounds__(256) void bnprep_kernel(
    float* __restrict__ stats, const float* __restrict__ gamma,
    const float* __restrict__ beta, float* __restrict__ sscale,
    float* __restrict__ sshift, int Nn)
{
    const int t = threadIdx.x;
    const float invN = 1.0f / (float)Nn;
    const float mu  = stats[t] * invN;
    const float var = stats[HD + t] * invN - mu * mu;
    const float inv = rsqrtf(var + BN_EPS);
    const float sc  = gamma[t] * inv;
    sscale[t] = sc;
    sshift[t] = beta[t] - mu * sc;
    stats[t] = 0.f;
    stats[HD + t] = 0.f;
}

// ---------------- CSR build (per call; edges are layer-invariant) -----------
__global__ __launch_bounds__(256) void hist_kernel(
    const int* __restrict__ dst, int* __restrict__ deg, int E)
{
    const int e = blockIdx.x * 256 + threadIdx.x;
    if (e < E) atomicAdd(&deg[dst[e]], 1);
}

__global__ __launch_bounds__(256) void scan1_kernel(
    const int* __restrict__ deg, int* __restrict__ partial,
    int* __restrict__ bsums, int n)
{
    __shared__ int tmp[256];
    const int i = blockIdx.x * 256 + threadIdx.x;
    const int v = (i < n) ? deg[i] : 0;
    tmp[threadIdx.x] = v;
    __syncthreads();
    for (int off = 1; off < 256; off <<= 1) {
        const int t = (threadIdx.x >= off) ? tmp[threadIdx.x - off] : 0;
        __syncthreads();
        tmp[threadIdx.x] += t;
        __syncthreads();
    }
    if (i < n) partial[i] = tmp[threadIdx.x] - v;
    if (threadIdx.x == 255) bsums[blockIdx.x] = tmp[255];
}

__global__ __launch_bounds__(512) void scan2_kernel(int* __restrict__ bsums, int nb)
{
    __shared__ int tmp[512];
    const int i = threadIdx.x;
    const int v = (i < nb) ? bsums[i] : 0;
    tmp[i] = v;
    __syncthreads();
    for (int off = 1; off < 512; off <<= 1) {
        const int t = (i >= off) ? tmp[i - off] : 0;
        __syncthreads();
        tmp[i] += t;
        __syncthreads();
    }
    if (i < nb) bsums[i] = tmp[i] - v;
}

__global__ __launch_bounds__(256) void scan3_kernel(
    const int* __restrict__ partial, const int* __restrict__ bsums,
    int* __restrict__ offs, int* __restrict__ cursor, int n)
{
    const int i = blockIdx.x * 256 + threadIdx.x;
    if (i < n) {
        const int o = partial[i] + bsums[blockIdx.x];
        offs[i] = o;
        cursor[i] = o;
    }
}

__global__ __launch_bounds__(256) void scatter_kernel(
    const int* __restrict__ src, const int* __restrict__ dst,
    int* __restrict__ cursor, int* __restrict__ srcSorted, int E)
{
    const int e = blockIdx.x * 256 + threadIdx.x;
    if (e >= E) return;
    const int p = atomicAdd(&cursor[dst[e]], 1);
    srcSorted[p] = src[e];
}

// ---------------------------------------------------------------------------
// out[n] = bf16( (1+eps)*y[n] + sum_{s in nbrs(n)} y[s] ),
// where y[i] = relu( z[i]*sscale + sshift )  (BN applied on the fly).
// 2-way unrolled gather: two independent loads in flight per iteration.
__global__ __launch_bounds__(256) void aggregate_kernel(
    const ushort_t* __restrict__ z, const int* __restrict__ offs,
    const int* __restrict__ deg, const int* __restrict__ srcSorted,
    const float* __restrict__ epsArr, int epsIdx,
    const float* __restrict__ sscale, const float* __restrict__ sshift,
    ushort_t* __restrict__ out)
{
    const int n = blockIdx.x * 4 + (threadIdx.x >> 6);
    const int t = threadIdx.x & 63;
    const float4 sc = *(const float4*)(sscale + t * 4);
    const float4 sh = *(const float4*)(sshift + t * 4);
    const int start = offs[n];
    const int dc = deg[n];
    float a0 = 0.f, a1 = 0.f, a2 = 0.f, a3 = 0.f;
    float b0 = 0.f, b1 = 0.f, b2 = 0.f, b3 = 0.f;
    int j = 0;
    for (; j + 1 < dc; j += 2) {
        const int s0 = srcSorted[start + j];
        const int s1 = srcSorted[start + j + 1];
        const ushort4 u = *(const ushort4*)(z + (size_t)s0 * HD + t * 4);
        const ushort4 v = *(const ushort4*)(z + (size_t)s1 * HD + t * 4);
        a0 += fmaxf(bf2f(u.x) * sc.x + sh.x, 0.f);
        a1 += fmaxf(bf2f(u.y) * sc.y + sh.y, 0.f);
        a2 += fmaxf(bf2f(u.z) * sc.z + sh.z, 0.f);
        a3 += fmaxf(bf2f(u.w) * sc.w + sh.w, 0.f);
        b0 += fmaxf(bf2f(v.x) * sc.x + sh.x, 0.f);
        b1 += fmaxf(bf2f(v.y) * sc.y + sh.y, 0.f);
        b2 += fmaxf(bf2f(v.z) * sc.z + sh.z, 0.f);
        b3 += fmaxf(bf2f(v.w) * sc.w + sh.w, 0.f);
    }
    if (j < dc) {
        const int s0 = srcSorted[start + j];
        const ushort4 u = *(const ushort4*)(z + (size_t)s0 * HD + t * 4);
        a0 += fmaxf(bf2f(u.x) * sc.x + sh.x, 0.f);
        a1 += fmaxf(bf2f(u.y) * sc.y + sh.y, 0.f);
        a2 += fmaxf(bf2f(u.z) * sc.z + sh.z, 0.f);
        a3 += fmaxf(bf2f(u.w) * sc.w + sh.w, 0.f);
    }
    a0 += b0; a1 += b1; a2 += b2; a3 += b3;
    const float se = 1.0f + epsArr[epsIdx];
    const ushort4 hs = *(const ushort4*)(z + (size_t)n * HD + t * 4);
    ushort4 o;
    o.x = f2bf(se * fmaxf(bf2f(hs.x) * sc.x + sh.x, 0.f) + a0);
    o.y = f2bf(se * fmaxf(bf2f(hs.y) * sc.y + sh.y, 0.f) + a1);
    o.z = f2bf(se * fmaxf(bf2f(hs.z) * sc.z + sh.z, 0.f) + a2);
    o.w = f2bf(se * fmaxf(bf2f(hs.w) * sc.w + sh.w, 0.f) + a3);
    *(ushort4*)(out + (size_t)n * HD + t * 4) = o;
}

// ---------------------------------------------------------------------------
// Fused mean-pool + head, BN on the fly. Wave w handles rows start+w, +4...;
// lane L handles cols 4L..4L+3 (ushort4). Two row-streams for ILP.
__global__ __launch_bounds__(256) void pool_head_kernel(
    const ushort_t* __restrict__ z, const int* __restrict__ batch,
    const float* __restrict__ sscale, const float* __restrict__ sshift,
    const float* __restrict__ Wp1, const float* __restrict__ bp1,
    const float* __restrict__ Wp2, const float* __restrict__ bp2,
    float* __restrict__ out)
{
    __shared__ float poolw[4][HD];
    __shared__ float pool[HD];
    __shared__ float red[128];
    __shared__ int seg[2];
    const int g = blockIdx.x;
    const int t = threadIdx.x;
    const int w = t >> 6;
    const int L = t & 63;
    if (t == 0) {
        int lo = 0, hi = NN;
        while (lo < hi) { const int m = (lo + hi) >> 1; if (batch[m] < g) lo = m + 1; else hi = m; }
        seg[0] = lo;
        hi = NN;
        while (lo < hi) { const int m = (lo + hi) >> 1; if (batch[m] < g + 1) lo = m + 1; else hi = m; }
        seg[1] = lo;
    }
    __syncthreads();
    const int start = seg[0], end = seg[1];
    const int c0 = L * 4;
    const float4 sc = *(const float4*)(sscale + c0);
    const float4 sh = *(const float4*)(sshift + c0);
    float a0 = 0.f, a1 = 0.f, a2 = 0.f, a3 = 0.f;
    float b0 = 0.f, b1 = 0.f, b2 = 0.f, b3 = 0.f;
    int r = start + w;
    for (; r + 4 < end; r += 8) {
        const ushort4 u = *(const ushort4*)(z + (size_t)r * HD + c0);
        const ushort4 v = *(const ushort4*)(z + (size_t)(r + 4) * HD + c0);
        a0 += fmaxf(bf2f(u.x) * sc.x + sh.x, 0.f);
        a1 += fmaxf(bf2f(u.y) * sc.y + sh.y, 0.f);
        a2 += fmaxf(bf2f(u.z) * sc.z + sh.z, 0.f);
        a3 += fmaxf(bf2f(u.w) * sc.w + sh.w, 0.f);
        b0 += fmaxf(bf2f(v.x) * sc.x + sh.x, 0.f);
        b1 += fmaxf(bf2f(v.y) * sc.y + sh.y, 0.f);
        b2 += fmaxf(bf2f(v.z) * sc.z + sh.z, 0.f);
        b3 += fmaxf(bf2f(v.w) * sc.w + sh.w, 0.f);
    }
    if (r < end) {
        const ushort4 u = *(const ushort4*)(z + (size_t)r * HD + c0);
        a0 += fmaxf(bf2f(u.x) * sc.x + sh.x, 0.f);
        a1 += fmaxf(bf2f(u.y) * sc.y + sh.y, 0.f);
        a2 += fmaxf(bf2f(u.z) * sc.z + sh.z, 0.f);
        a3 += fmaxf(bf2f(u.w) * sc.w + sh.w, 0.f);
    }
    poolw[w][c0 + 0] = a0 + b0;
    poolw[w][c0 + 1] = a1 + b1;
    poolw[w][c0 + 2] = a2 + b2;
    poolw[w][c0 + 3] = a3 + b3;
    __syncthreads();
    const float invC = 1.0f / (float)max(end - start, 1);
    pool[t] = (poolw[0][t] + poolw[1][t] + poolw[2][t] + poolw[3][t]) * invC;
    __syncthreads();
    if (t < 128) {
        float acc = 0.f;
#pragma unroll 4
        for (int k = 0; k < HD; ++k)
            acc += pool[k] * Wp1[k * 128 + t];
        red[t] = fmaxf(acc + bp1[t], 0.f) * Wp2[t];
    }
    __syncthreads();
    for (int sft = 64; sft > 0; sft >>= 1) {
        if (t < sft) red[t] += red[t + sft];
        __syncthreads();
    }
    if (t == 0) out[g] = red[0] + bp2[0];
}

// ---------------------------------------------------------------------------
extern "C" void kernel_launch(void* const* d_in, const int* in_sizes, int n_in,
                              void* d_out, int out_size, void* d_ws, size_t ws_size,
                              hipStream_t stream)
{
    const float* x     = (const float*)d_in[0];
    const int*   ei    = (const int*)  d_in[1];
    const int*   batch = (const int*)  d_in[2];
    const float* W_in  = (const float*)d_in[3];
    const float* b_in  = (const float*)d_in[4];
    const float* eps   = (const float*)d_in[5];
    const float* W1    = (const float*)d_in[6];
    const float* b1    = (const float*)d_in[7];
    const float* W2    = (const float*)d_in[8];
    const float* b2    = (const float*)d_in[9];
    const float* gamma = (const float*)d_in[10];
    const float* beta  = (const float*)d_in[11];
    const float* Wp1   = (const float*)d_in[12];
    const float* bp1   = (const float*)d_in[13];
    const float* Wp2   = (const float*)d_in[14];
    const float* bp2   = (const float*)d_in[15];

    const int* srcIdx = ei;
    const int* dstIdx = ei + EE;

    // ---- workspace layout ----
    char* p = (char*)d_ws;
    ushort_t* zbuf    = (ushort_t*)p;  p += (size_t)NP * HD  * 2;   // pre-BN acts
    ushort_t* abuf    = (ushort_t*)p;  p += (size_t)NP * HD  * 2;   // aggregate out
    ushort_t* hidden  = (ushort_t*)p;  p += (size_t)NP * HD2 * 2;   // MLP hidden (x_bf alias)
    ushort_t* W1T     = (ushort_t*)p;  p += (size_t)NL * HD2 * HD * 2;
    ushort_t* W2T     = (ushort_t*)p;  p += (size_t)NL * HD * HD2 * 2;
    ushort_t* WinT    = (ushort_t*)p;  p += (size_t)HD * DIN * 2;
    int* deg          = (int*)p;       p += (size_t)NN * 4;
    int* partial      = (int*)p;       p += (size_t)NN * 4;
    int* bsums        = (int*)p;       p += 512 * 4;
    int* offs         = (int*)p;       p += (size_t)NN * 4;
    int* cursor       = (int*)p;       p += (size_t)NN * 4;
    int* srcSorted    = (int*)p;       p += (size_t)EE * 4;
    float* stats      = (float*)p;     p += 2 * HD * 4;
    float* sscale     = (float*)p;     p += HD * 4;
    float* sshift     = (float*)p;     p += HD * 4;
    ushort_t* x_bf    = hidden;        // GEMM0 A; clobbered later by GEMM1 out

    const int nb = (NN + 255) / 256;   // 391
    const int GEMM_LDS = 53248;        // 3 x 16KB stages + 4KB stats partials

    // ---- BN identity + stats zero ----
    init_bn_kernel<<<1, 256, 0, stream>>>(sscale, sshift, stats);

    // ---- weight conversion (bf16, transposed) ----
    transpose_cvt_kernel<<<dim3(HD / 32, DIN / 32), 256, 0, stream>>>(W_in, WinT, DIN, HD);
    for (int l = 0; l < NL; ++l) {
        transpose_cvt_kernel<<<dim3(HD2 / 32, HD / 32), 256, 0, stream>>>(
            W1 + (size_t)l * HD * HD2, W1T + (size_t)l * HD2 * HD, HD, HD2);
        transpose_cvt_kernel<<<dim3(HD / 32, HD2 / 32), 256, 0, stream>>>(
            W2 + (size_t)l * HD2 * HD, W2T + (size_t)l * HD * HD2, HD2, HD);
    }
    cvt_kernel<<<(int)(((long)NN * DIN / 4 + 255) / 256), 256, 0, stream>>>(
        x, x_bf, (long)NN * DIN / 4);

    // ---- CSR build (once; edges layer-invariant) ----
    zero_kernel<<<(NN / 4 + 255) / 256, 256, 0, stream>>>((float*)deg, NN / 4);
    hist_kernel<<<(EE + 255) / 256, 256, 0, stream>>>(dstIdx, deg, EE);
    scan1_kernel<<<nb, 256, 0, stream>>>(deg, partial, bsums, NN);
    scan2_kernel<<<1, 512, 0, stream>>>(bsums, nb);
    scan3_kernel<<<nb, 256, 0, stream>>>(partial, bsums, offs, cursor, NN);
    scatter_kernel<<<(EE + 255) / 256, 256, 0, stream>>>(srcIdx, dstIdx, cursor, srcSorted, EE);

    // ---- input projection: zbuf = relu(x @ W_in + b_in)  (identity BN) ----
    gemm_bf16<<<dim3(NP / 128, HD / 128), 256, GEMM_LDS, stream>>>(
        x_bf, DIN, WinT, DIN, b_in, zbuf, HD, DIN, 1, 0, nullptr, 0);

    // ---- GIN layers ----
    for (int l = 0; l < NL; ++l) {
        aggregate_kernel<<<NN / 4, 256, 0, stream>>>(
            zbuf, offs, deg, srcSorted, eps, l, sscale, sshift, abuf);

        gemm_bf16<<<dim3(NP / 128, HD2 / 128), 256, GEMM_LDS, stream>>>(
            abuf, HD, W1T + (size_t)l * HD2 * HD, HD,
            b1 + (size_t)l * HD2, hidden, HD2, HD, 1, 0, nullptr, 0);

        gemm_bf16<<<dim3(NP / 128, HD / 128), 256, GEMM_LDS, stream>>>(
            hidden, HD2, W2T + (size_t)l * HD * HD2, HD2,
            b2 + (size_t)l * HD, zbuf, HD, HD2, 0, 1, stats, NN);

        bnprep_kernel<<<1, 256, 0, stream>>>(
            stats, gamma + (size_t)l * HD, beta + (size_t)l * HD, sscale, sshift, NN);
    }

    // ---- fused mean pool + head (BN on the fly) ----
    pool_head_kernel<<<NG, 256, 0, stream>>>(zbuf, batch, sscale, sshift,
                                             Wp1, bp1, Wp2, bp2, (float*)d_out);
}

// Round 10
// 909.927 us; speedup vs baseline: 1.2796x; 1.0374x over previous
//
#include <hip/hip_runtime.h>

#define NN 100000
#define NP 100096          // 782 * 128, padded row count
#define EE 300000
#define DIN 128
#define HD  256
#define HD2 512
#define NL  4
#define NG  512
#define BN_EPS 1e-5f

typedef __attribute__((ext_vector_type(8))) short s8v;      // bf16x8 frag (4 VGPRs)
typedef __attribute__((ext_vector_type(4))) float f4v;      // fp32x4 acc

typedef unsigned short ushort_t;

// float -> bf16, round-to-nearest-even
static __device__ inline ushort_t f2bf(float f) {
    unsigned u = __float_as_uint(f);
    unsigned r = (u + 0x7fffu + ((u >> 16) & 1u)) >> 16;
    return (ushort_t)r;
}
static __device__ inline float bf2f(ushort_t h) {
    return __uint_as_float(((unsigned)h) << 16);
}
// bf16 pair unpack from packed u32: low half needs shift, high half mask-only
static __device__ inline float blo(unsigned v) { return __uint_as_float(v << 16); }
static __device__ inline float bhi(unsigned v) { return __uint_as_float(v & 0xffff0000u); }

// async global->LDS, 16B per lane; LDS dest = uniform base + lane*16
#define GLOAD_LDS16(g, l) __builtin_amdgcn_global_load_lds( \
    (const __attribute__((address_space(1))) unsigned int*)(const void*)(g), \
    (__attribute__((address_space(3))) unsigned int*)(void*)(l), 16, 0, 0)

// s_waitcnt immediates: vmcnt[3:0] | expcnt(7)<<4 | lgkmcnt(15)<<8 | vmcnt[5:4]<<14
#define WAITCNT_VM8 0xF78
#define WAITCNT_VM4 0xF74
#define WAITCNT_VM0 0xF70

// ---------------------------------------------------------------------------
// bf16 MFMA GEMM (r9 shape — measured local optimum: 77 us @ K=512).
// Block tile 128x128, BK=32, 4 waves, 3-stage circular LDS pipeline
// (16 KB/stage), graded vmcnt(8)/(4)/(0). 53 KB LDS -> 3 blocks/CU.
// doStats: column sum/sumsq of fp32 output into stats via block reduce+atomics.
// ---------------------------------------------------------------------------
__global__ __launch_bounds__(256) void gemm_bf16(
    const ushort_t* __restrict__ A, int lda,
    const ushort_t* __restrict__ BT, int ldb,
    const float* __restrict__ bias,
    ushort_t* __restrict__ C, int ldc,
    int K, int doRelu,
    int doStats, float* __restrict__ stats, int Mvalid)
{
    extern __shared__ char smem[];
    ushort_t* lds = (ushort_t*)smem;            // 3 stages x (A 8KB | B 8KB)
    ushort_t* Cs  = lds;                        // epilogue reuse (32 KB)
    float* ssum   = (float*)(smem + 49152);     // [4][128]
    float* ssq    = ssum + 512;

    const int tid  = threadIdx.x;
    const int w    = tid >> 6;
    const int L    = tid & 63;
    const int lm   = L & 15;
    const int q    = L >> 4;
    const int row0 = blockIdx.x * 128;
    const int col0 = blockIdx.y * 128;

    const ushort_t* gAbase = A  + (size_t)lm * lda;
    const ushort_t* gBbase = BT + (size_t)lm * ldb;

    f4v acc[2][8] = {};

    const int niter = K >> 5;

    #define STAGE(buf, k0) do {                                              \
        ushort_t* As_ = lds + (buf) * 8192;                                  \
        ushort_t* Bs_ = As_ + 4096;                                          \
        const int kk_ = (k0) + q * 8;                                        \
        _Pragma("unroll")                                                    \
        for (int i_ = 0; i_ < 2; ++i_) {                                     \
            const int tl_ = w * 2 + i_;                                      \
            GLOAD_LDS16(gAbase + (size_t)(row0 + tl_ * 16) * lda + kk_,      \
                        As_ + tl_ * 512);                                    \
            GLOAD_LDS16(gBbase + (size_t)(col0 + tl_ * 16) * ldb + kk_,      \
                        Bs_ + tl_ * 512);                                    \
        }                                                                    \
    } while (0)

    STAGE(0, 0);
    if (niter > 1) STAGE(1, 32);
    if (niter > 2) STAGE(2, 64);

    int cur = 0;
    for (int it = 0; it < niter; ++it) {
        const int rem = niter - 1 - it;
        if (rem >= 2)      __builtin_amdgcn_s_waitcnt(WAITCNT_VM8);
        else if (rem == 1) __builtin_amdgcn_s_waitcnt(WAITCNT_VM4);
        else               __builtin_amdgcn_s_waitcnt(WAITCNT_VM0);
        __builtin_amdgcn_s_barrier();

        const ushort_t* Ab = lds + cur * 8192;
        const ushort_t* Bb = Ab + 4096;
        s8v a0 = *(const s8v*)&Ab[(2 * w)     * 512 + L * 8];
        s8v a1 = *(const s8v*)&Ab[(2 * w + 1) * 512 + L * 8];
#pragma unroll
        for (int nt = 0; nt < 8; ++nt) {
            s8v b = *(const s8v*)&Bb[nt * 512 + L * 8];
            acc[0][nt] = __builtin_amdgcn_mfma_f32_16x16x32_bf16(a0, b, acc[0][nt], 0, 0, 0);
            acc[1][nt] = __builtin_amdgcn_mfma_f32_16x16x32_bf16(a1, b, acc[1][nt], 0, 0, 0);
        }
        __builtin_amdgcn_s_barrier();
        if (it + 3 < niter) STAGE(cur, (it + 3) * 32);
        cur = (cur == 2) ? 0 : cur + 1;
    }
    #undef STAGE

    __syncthreads();

    // epilogue: bias + relu + cvt; C/D frag: col = lm, row = q*4 + r
    float cs[8] = {};
    float cq[8] = {};
#pragma unroll
    for (int mt = 0; mt < 2; ++mt) {
#pragma unroll
        for (int nt = 0; nt < 8; ++nt) {
            const float bj = bias[col0 + nt * 16 + lm];
            f4v v = acc[mt][nt];
#pragma unroll
            for (int r = 0; r < 4; ++r) {
                float f = v[r] + bj;
                if (doRelu) f = fmaxf(f, 0.f);
                const int row = (2 * w + mt) * 16 + q * 4 + r;
                const int col = nt * 16 + lm;
                Cs[row * 128 + col] = f2bf(f);
                if (doStats && (row0 + row) < Mvalid) {
                    cs[nt] += f;
                    cq[nt] += f * f;
                }
            }
        }
    }
    if (doStats) {
#pragma unroll
        for (int nt = 0; nt < 8; ++nt) {
            float s = cs[nt], sq = cq[nt];
            s  += __shfl_xor(s, 16, 64);  s  += __shfl_xor(s, 32, 64);
            sq += __shfl_xor(sq, 16, 64); sq += __shfl_xor(sq, 32, 64);
            cs[nt] = s; cq[nt] = sq;
        }
    }
    __syncthreads();
    if (doStats && q == 0) {
#pragma unroll
        for (int nt = 0; nt < 8; ++nt) {
            ssum[w * 128 + nt * 16 + lm] = cs[nt];
            ssq [w * 128 + nt * 16 + lm] = cq[nt];
        }
    }
#pragma unroll
    for (int i = 0; i < 8; ++i) {
        const int idx = i * 256 + tid;
        const int row = idx >> 4, ch = idx & 15;
        s8v val = *(const s8v*)&Cs[row * 128 + ch * 8];
        *(s8v*)(C + (size_t)(row0 + row) * ldc + col0 + ch * 8) = val;
    }
    if (doStats) {
        __syncthreads();
        if (tid < 128) {
            const float s  = ssum[tid] + ssum[128 + tid] + ssum[256 + tid] + ssum[384 + tid];
            const float sq = ssq[tid]  + ssq[128 + tid]  + ssq[256 + tid]  + ssq[384 + tid];
            unsafeAtomicAdd(&stats[col0 + tid], s);
            unsafeAtomicAdd(&stats[HD + col0 + tid], sq);
        }
    }
}

// ---------------------------------------------------------------------------
// Batched transpose + fp32->bf16: out[z][c][r] = in[z][r][c]; blockIdx.z = batch.
__global__ __launch_bounds__(256) void transpose_cvt_kernel(
    const float* __restrict__ in, ushort_t* __restrict__ out, int R, int C,
    long inStride, long outStride)
{
    __shared__ float tile[32][33];
    const float* inp  = in  + (size_t)blockIdx.z * inStride;
    ushort_t*    outp = out + (size_t)blockIdx.z * outStride;
    const int bx = blockIdx.x * 32;
    const int by = blockIdx.y * 32;
    const int tx = threadIdx.x & 31;
    const int ty = threadIdx.x >> 5;
#pragma unroll
    for (int i = 0; i < 32; i += 8)
        tile[ty + i][tx] = inp[(size_t)(by + ty + i) * C + bx + tx];
    __syncthreads();
#pragma unroll
    for (int i = 0; i < 32; i += 8)
        outp[(size_t)(bx + ty + i) * R + by + tx] = f2bf(tile[tx][ty + i]);
}

__global__ __launch_bounds__(256) void cvt_kernel(
    const float* __restrict__ in, ushort_t* __restrict__ out, long n4)
{
    const long i = (long)blockIdx.x * 256 + threadIdx.x;
    if (i >= n4) return;
    const float4 v = ((const float4*)in)[i];
    ushort4 o;
    o.x = f2bf(v.x); o.y = f2bf(v.y); o.z = f2bf(v.z); o.w = f2bf(v.w);
    ((ushort4*)out)[i] = o;
}

__global__ __launch_bounds__(256) void zero_kernel(float* __restrict__ p, long n4)
{
    const long i = (long)blockIdx.x * 256 + threadIdx.x;
    if (i < n4) ((float4*)p)[i] = make_float4(0.f, 0.f, 0.f, 0.f);
}

// identity scale/shift + zeroed stats (once per call, before layer 0)
__global__ __launch_bounds__(256) void init_bn_kernel(
    float* __restrict__ sscale, float* __restrict__ sshift,
    float* __restrict__ stats)
{
    const int t = threadIdx.x;
    sscale[t] = 1.f;
    sshift[t] = 0.f;
    stats[t] = 0.f;
    stats[HD + t] = 0.f;
}

// scale/shift from stats; re-zero stats for the next layer
__global__ __launch_bounds__(256) void bnprep_kernel(
    float* __restrict__ stats, const float* __restrict__ gamma,
    const float* __restrict__ beta, float* __restrict__ sscale,
    float* __restrict__ sshift, int Nn)
{
    const int t = threadIdx.x;
    const float invN = 1.0f / (float)Nn;
    const float mu  = stats[t] * invN;
    const float var = stats[HD + t] * invN - mu * mu;
    const float inv = rsqrtf(var + BN_EPS);
    const float sc  = gamma[t] * inv;
    sscale[t] = sc;
    sshift[t] = beta[t] - mu * sc;
    stats[t] = 0.f;
    stats[HD + t] = 0.f;
}

// ---------------- CSR build (per call; edges are layer-invariant) -----------
__global__ __launch_bounds__(256) void hist_kernel(
    const int* __restrict__ dst, int* __restrict__ deg, int E)
{
    const int e = blockIdx.x * 256 + threadIdx.x;
    if (e < E) atomicAdd(&deg[dst[e]], 1);
}

__global__ __launch_bounds__(256) void scan1_kernel(
    const int* __restrict__ deg, int* __restrict__ partial,
    int* __restrict__ bsums, int n)
{
    __shared__ int tmp[256];
    const int i = blockIdx.x * 256 + threadIdx.x;
    const int v = (i < n) ? deg[i] : 0;
    tmp[threadIdx.x] = v;
    __syncthreads();
    for (int off = 1; off < 256; off <<= 1) {
        const int t = (threadIdx.x >= off) ? tmp[threadIdx.x - off] : 0;
        __syncthreads();
        tmp[threadIdx.x] += t;
        __syncthreads();
    }
    if (i < n) partial[i] = tmp[threadIdx.x] - v;
    if (threadIdx.x == 255) bsums[blockIdx.x] = tmp[255];
}

__global__ __launch_bounds__(512) void scan2_kernel(int* __restrict__ bsums, int nb)
{
    __shared__ int tmp[512];
    const int i = threadIdx.x;
    const int v = (i < nb) ? bsums[i] : 0;
    tmp[i] = v;
    __syncthreads();
    for (int off = 1; off < 512; off <<= 1) {
        const int t = (i >= off) ? tmp[i - off] : 0;
        __syncthreads();
        tmp[i] += t;
        __syncthreads();
    }
    if (i < nb) bsums[i] = tmp[i] - v;
}

__global__ __launch_bounds__(256) void scan3_kernel(
    const int* __restrict__ partial, const int* __restrict__ bsums,
    int* __restrict__ offs, int* __restrict__ cursor, int n)
{
    const int i = blockIdx.x * 256 + threadIdx.x;
    if (i < n) {
        const int o = partial[i] + bsums[blockIdx.x];
        offs[i] = o;
        cursor[i] = o;
    }
}

__global__ __launch_bounds__(256) void scatter_kernel(
    const int* __restrict__ src, const int* __restrict__ dst,
    int* __restrict__ cursor, int* __restrict__ srcSorted, int E)
{
    const int e = blockIdx.x * 256 + threadIdx.x;
    if (e >= E) return;
    const int p = atomicAdd(&cursor[dst[e]], 1);
    srcSorted[p] = src[e];
}

// ---------------------------------------------------------------------------
// out[n] = bf16( (1+eps)*y[n] + sum_{s in nbrs(n)} y[s] ),
// y[i] = relu( z[i]*sscale + sshift )  (BN on the fly).
// v2: 2 nodes per wave (half-wave each), lane covers 8 cols via one 16B
// uint4 load -> full 512B row per half-wave; 2-way neighbor unroll for MLP.
__global__ __launch_bounds__(256) void aggregate_kernel(
    const ushort_t* __restrict__ z, const int* __restrict__ offs,
    const int* __restrict__ deg, const int* __restrict__ srcSorted,
    const float* __restrict__ epsArr, int epsIdx,
    const float* __restrict__ sscale, const float* __restrict__ sshift,
    ushort_t* __restrict__ out)
{
    const int n = blockIdx.x * 8 + (threadIdx.x >> 5);   // 8 nodes / 256 thr
    const int L = threadIdx.x & 31;
    const int c0 = L * 8;
    const float4 scA = *(const float4*)(sscale + c0);
    const float4 scB = *(const float4*)(sscale + c0 + 4);
    const float4 shA = *(const float4*)(sshift + c0);
    const float4 shB = *(const float4*)(sshift + c0 + 4);
    const int start = offs[n];
    const int dc = deg[n];
    float a[8] = {};
    float b[8] = {};
    int j = 0;
    for (; j + 1 < dc; j += 2) {
        const int s0 = srcSorted[start + j];
        const int s1 = srcSorted[start + j + 1];
        const uint4 u = *(const uint4*)(z + (size_t)s0 * HD + c0);
        const uint4 v = *(const uint4*)(z + (size_t)s1 * HD + c0);
        a[0] += fmaxf(blo(u.x) * scA.x + shA.x, 0.f);
        a[1] += fmaxf(bhi(u.x) * scA.y + shA.y, 0.f);
        a[2] += fmaxf(blo(u.y) * scA.z + shA.z, 0.f);
        a[3] += fmaxf(bhi(u.y) * scA.w + shA.w, 0.f);
        a[4] += fmaxf(blo(u.z) * scB.x + shB.x, 0.f);
        a[5] += fmaxf(bhi(u.z) * scB.y + shB.y, 0.f);
        a[6] += fmaxf(blo(u.w) * scB.z + shB.z, 0.f);
        a[7] += fmaxf(bhi(u.w) * scB.w + shB.w, 0.f);
        b[0] += fmaxf(blo(v.x) * scA.x + shA.x, 0.f);
        b[1] += fmaxf(bhi(v.x) * scA.y + shA.y, 0.f);
        b[2] += fmaxf(blo(v.y) * scA.z + shA.z, 0.f);
        b[3] += fmaxf(bhi(v.y) * scA.w + shA.w, 0.f);
        b[4] += fmaxf(blo(v.z) * scB.x + shB.x, 0.f);
        b[5] += fmaxf(bhi(v.z) * scB.y + shB.y, 0.f);
        b[6] += fmaxf(blo(v.w) * scB.z + shB.z, 0.f);
        b[7] += fmaxf(bhi(v.w) * scB.w + shB.w, 0.f);
    }
    if (j < dc) {
        const int s0 = srcSorted[start + j];
        const uint4 u = *(const uint4*)(z + (size_t)s0 * HD + c0);
        a[0] += fmaxf(blo(u.x) * scA.x + shA.x, 0.f);
        a[1] += fmaxf(bhi(u.x) * scA.y + shA.y, 0.f);
        a[2] += fmaxf(blo(u.y) * scA.z + shA.z, 0.f);
        a[3] += fmaxf(bhi(u.y) * scA.w + shA.w, 0.f);
        a[4] += fmaxf(blo(u.z) * scB.x + shB.x, 0.f);
        a[5] += fmaxf(bhi(u.z) * scB.y + shB.y, 0.f);
        a[6] += fmaxf(blo(u.w) * scB.z + shB.z, 0.f);
        a[7] += fmaxf(bhi(u.w) * scB.w + shB.w, 0.f);
    }
#pragma unroll
    for (int k = 0; k < 8; ++k) a[k] += b[k];
    const float se = 1.0f + epsArr[epsIdx];
    const uint4 hs = *(const uint4*)(z + (size_t)n * HD + c0);
    float y[8];
    y[0] = se * fmaxf(blo(hs.x) * scA.x + shA.x, 0.f) + a[0];
    y[1] = se * fmaxf(bhi(hs.x) * scA.y + shA.y, 0.f) + a[1];
    y[2] = se * fmaxf(blo(hs.y) * scA.z + shA.z, 0.f) + a[2];
    y[3] = se * fmaxf(bhi(hs.y) * scA.w + shA.w, 0.f) + a[3];
    y[4] = se * fmaxf(blo(hs.z) * scB.x + shB.x, 0.f) + a[4];
    y[5] = se * fmaxf(bhi(hs.z) * scB.y + shB.y, 0.f) + a[5];
    y[6] = se * fmaxf(blo(hs.w) * scB.z + shB.z, 0.f) + a[6];
    y[7] = se * fmaxf(bhi(hs.w) * scB.w + shB.w, 0.f) + a[7];
    uint4 o;
    o.x = (unsigned)f2bf(y[0]) | ((unsigned)f2bf(y[1]) << 16);
    o.y = (unsigned)f2bf(y[2]) | ((unsigned)f2bf(y[3]) << 16);
    o.z = (unsigned)f2bf(y[4]) | ((unsigned)f2bf(y[5]) << 16);
    o.w = (unsigned)f2bf(y[6]) | ((unsigned)f2bf(y[7]) << 16);
    *(uint4*)(out + (size_t)n * HD + c0) = o;
}

// ---------------------------------------------------------------------------
// Fused mean-pool + head, BN on the fly (r7 shape — measured ~20 us).
__global__ __launch_bounds__(256) void pool_head_kernel(
    const ushort_t* __restrict__ z, const int* __restrict__ batch,
    const float* __restrict__ sscale, const float* __restrict__ sshift,
    const float* __restrict__ Wp1, const float* __restrict__ bp1,
    const float* __restrict__ Wp2, const float* __restrict__ bp2,
    float* __restrict__ out)
{
    __shared__ float poolw[4][HD];
    __shared__ float pool[HD];
    __shared__ float red[128];
    __shared__ int seg[2];
    const int g = blockIdx.x;
    const int t = threadIdx.x;
    const int w = t >> 6;
    const int L = t & 63;
    if (t == 0) {
        int lo = 0, hi = NN;
        while (lo < hi) { const int m = (lo + hi) >> 1; if (batch[m] < g) lo = m + 1; else hi = m; }
        seg[0] = lo;
        hi = NN;
        while (lo < hi) { const int m = (lo + hi) >> 1; if (batch[m] < g + 1) lo = m + 1; else hi = m; }
        seg[1] = lo;
    }
    __syncthreads();
    const int start = seg[0], end = seg[1];
    const int c0 = L * 4;
    const float4 sc = *(const float4*)(sscale + c0);
    const float4 sh = *(const float4*)(sshift + c0);
    float a0 = 0.f, a1 = 0.f, a2 = 0.f, a3 = 0.f;
    float b0 = 0.f, b1 = 0.f, b2 = 0.f, b3 = 0.f;
    int r = start + w;
    for (; r + 4 < end; r += 8) {
        const ushort4 u = *(const ushort4*)(z + (size_t)r * HD + c0);
        const ushort4 v = *(const ushort4*)(z + (size_t)(r + 4) * HD + c0);
        a0 += fmaxf(bf2f(u.x) * sc.x + sh.x, 0.f);
        a1 += fmaxf(bf2f(u.y) * sc.y + sh.y, 0.f);
        a2 += fmaxf(bf2f(u.z) * sc.z + sh.z, 0.f);
        a3 += fmaxf(bf2f(u.w) * sc.w + sh.w, 0.f);
        b0 += fmaxf(bf2f(v.x) * sc.x + sh.x, 0.f);
        b1 += fmaxf(bf2f(v.y) * sc.y + sh.y, 0.f);
        b2 += fmaxf(bf2f(v.z) * sc.z + sh.z, 0.f);
        b3 += fmaxf(bf2f(v.w) * sc.w + sh.w, 0.f);
    }
    if (r < end) {
        const ushort4 u = *(const ushort4*)(z + (size_t)r * HD + c0);
        a0 += fmaxf(bf2f(u.x) * sc.x + sh.x, 0.f);
        a1 += fmaxf(bf2f(u.y) * sc.y + sh.y, 0.f);
        a2 += fmaxf(bf2f(u.z) * sc.z + sh.z, 0.f);
        a3 += fmaxf(bf2f(u.w) * sc.w + sh.w, 0.f);
    }
    poolw[w][c0 + 0] = a0 + b0;
    poolw[w][c0 + 1] = a1 + b1;
    poolw[w][c0 + 2] = a2 + b2;
    poolw[w][c0 + 3] = a3 + b3;
    __syncthreads();
    const float invC = 1.0f / (float)max(end - start, 1);
    pool[t] = (poolw[0][t] + poolw[1][t] + poolw[2][t] + poolw[3][t]) * invC;
    __syncthreads();
    if (t < 128) {
        float acc = 0.f;
#pragma unroll 4
        for (int k = 0; k < HD; ++k)
            acc += pool[k] * Wp1[k * 128 + t];
        red[t] = fmaxf(acc + bp1[t], 0.f) * Wp2[t];
    }
    __syncthreads();
    for (int sft = 64; sft > 0; sft >>= 1) {
        if (t < sft) red[t] += red[t + sft];
        __syncthreads();
    }
    if (t == 0) out[g] = red[0] + bp2[0];
}

// ---------------------------------------------------------------------------
extern "C" void kernel_launch(void* const* d_in, const int* in_sizes, int n_in,
                              void* d_out, int out_size, void* d_ws, size_t ws_size,
                              hipStream_t stream)
{
    const float* x     = (const float*)d_in[0];
    const int*   ei    = (const int*)  d_in[1];
    const int*   batch = (const int*)  d_in[2];
    const float* W_in  = (const float*)d_in[3];
    const float* b_in  = (const float*)d_in[4];
    const float* eps   = (const float*)d_in[5];
    const float* W1    = (const float*)d_in[6];
    const float* b1    = (const float*)d_in[7];
    const float* W2    = (const float*)d_in[8];
    const float* b2    = (const float*)d_in[9];
    const float* gamma = (const float*)d_in[10];
    const float* beta  = (const float*)d_in[11];
    const float* Wp1   = (const float*)d_in[12];
    const float* bp1   = (const float*)d_in[13];
    const float* Wp2   = (const float*)d_in[14];
    const float* bp2   = (const float*)d_in[15];

    const int* srcIdx = ei;
    const int* dstIdx = ei + EE;

    // ---- workspace layout ----
    char* p = (char*)d_ws;
    ushort_t* zbuf    = (ushort_t*)p;  p += (size_t)NP * HD  * 2;   // pre-BN acts
    ushort_t* abuf    = (ushort_t*)p;  p += (size_t)NP * HD  * 2;   // aggregate out
    ushort_t* hidden  = (ushort_t*)p;  p += (size_t)NP * HD2 * 2;   // MLP hidden (x_bf alias)
    ushort_t* W1T     = (ushort_t*)p;  p += (size_t)NL * HD2 * HD * 2;
    ushort_t* W2T     = (ushort_t*)p;  p += (size_t)NL * HD * HD2 * 2;
    ushort_t* WinT    = (ushort_t*)p;  p += (size_t)HD * DIN * 2;
    int* deg          = (int*)p;       p += (size_t)NN * 4;
    int* partial      = (int*)p;       p += (size_t)NN * 4;
    int* bsums        = (int*)p;       p += 512 * 4;
    int* offs         = (int*)p;       p += (size_t)NN * 4;
    int* cursor       = (int*)p;       p += (size_t)NN * 4;
    int* srcSorted    = (int*)p;       p += (size_t)EE * 4;
    float* stats      = (float*)p;     p += 2 * HD * 4;
    float* sscale     = (float*)p;     p += HD * 4;
    float* sshift     = (float*)p;     p += HD * 4;
    ushort_t* x_bf    = hidden;        // GEMM0 A; clobbered later by GEMM1 out

    const int nb = (NN + 255) / 256;   // 391
    const int GEMM_LDS = 53248;        // 3 x 16KB stages + 4KB stats partials

    // ---- BN identity + stats zero ----
    init_bn_kernel<<<1, 256, 0, stream>>>(sscale, sshift, stats);

    // ---- weight conversion (bf16, transposed; layer-batched) ----
    transpose_cvt_kernel<<<dim3(HD / 32, DIN / 32, 1), 256, 0, stream>>>(
        W_in, WinT, DIN, HD, 0, 0);
    transpose_cvt_kernel<<<dim3(HD2 / 32, HD / 32, NL), 256, 0, stream>>>(
        W1, W1T, HD, HD2, (long)HD * HD2, (long)HD2 * HD);
    transpose_cvt_kernel<<<dim3(HD / 32, HD2 / 32, NL), 256, 0, stream>>>(
        W2, W2T, HD2, HD, (long)HD2 * HD, (long)HD * HD2);
    cvt_kernel<<<(int)(((long)NN * DIN / 4 + 255) / 256), 256, 0, stream>>>(
        x, x_bf, (long)NN * DIN / 4);

    // ---- CSR build (once; edges layer-invariant) ----
    zero_kernel<<<(NN / 4 + 255) / 256, 256, 0, stream>>>((float*)deg, NN / 4);
    hist_kernel<<<(EE + 255) / 256, 256, 0, stream>>>(dstIdx, deg, EE);
    scan1_kernel<<<nb, 256, 0, stream>>>(deg, partial, bsums, NN);
    scan2_kernel<<<1, 512, 0, stream>>>(bsums, nb);
    scan3_kernel<<<nb, 256, 0, stream>>>(partial, bsums, offs, cursor, NN);
    scatter_kernel<<<(EE + 255) / 256, 256, 0, stream>>>(srcIdx, dstIdx, cursor, srcSorted, EE);

    // ---- input projection: zbuf = relu(x @ W_in + b_in)  (identity BN) ----
    gemm_bf16<<<dim3(NP / 128, HD / 128), 256, GEMM_LDS, stream>>>(
        x_bf, DIN, WinT, DIN, b_in, zbuf, HD, DIN, 1, 0, nullptr, 0);

    // ---- GIN layers ----
    for (int l = 0; l < NL; ++l) {
        aggregate_kernel<<<NN / 8, 256, 0, stream>>>(
            zbuf, offs, deg, srcSorted, eps, l, sscale, sshift, abuf);

        gemm_bf16<<<dim3(NP / 128, HD2 / 128), 256, GEMM_LDS, stream>>>(
            abuf, HD, W1T + (size_t)l * HD2 * HD, HD,
            b1 + (size_t)l * HD2, hidden, HD2, HD, 1, 0, nullptr, 0);

        gemm_bf16<<<dim3(NP / 128, HD / 128), 256, GEMM_LDS, stream>>>(
            hidden, HD2, W2T + (size_t)l * HD * HD2, HD2,
            b2 + (size_t)l * HD, zbuf, HD, HD2, 0, 1, stats, NN);

        bnprep_kernel<<<1, 256, 0, stream>>>(
            stats, gamma + (size_t)l * HD, beta + (size_t)l * HD, sscale, sshift, NN);
    }

    // ---- fused mean pool + head (BN on the fly) ----
    pool_head_kernel<<<NG, 256, 0, stream>>>(zbuf, batch, sscale, sshift,
                                             Wp1, bp1, Wp2, bp2, (float*)d_out);
}